// Round 3
// baseline (1714.161 us; speedup 1.0000x reference)
//
#include <hip/hip_runtime.h>

// Problem constants
#define N_NODES    117760
#define N_EDGES    3768320
#define IN_FEAT    115
#define HIDDEN     64
#define NPG        115
#define NUM_GRAPHS 1024
#define HC2        256
#define FDIM       (NPG*HIDDEN)   // 7360
#define NB         460            // buckets (N_NODES / BNODES exactly)
#define BNODES     256            // dst nodes per bucket
#define RPB        8192           // edges per partition block (N_EDGES/RPB = 460)

// adj entry: .x = src | (dstlow<<17)   (src < 2^17, dstlow < 256), .y = bits(ew)

__device__ __forceinline__ float bf2f(unsigned short u) {
    return __uint_as_float(((unsigned)u) << 16);
}
__device__ __forceinline__ unsigned short f2bf(float f) {
    unsigned x = __float_as_uint(f);
    unsigned r = x + 0x7FFFu + ((x >> 16) & 1u);   // RNE
    return (unsigned short)(r >> 16);
}

// ---------------- pass 1: global bucket histogram ----------------
__global__ __launch_bounds__(256) void k_hist(const int* __restrict__ ei,
                                              unsigned* __restrict__ ghist) {
    __shared__ unsigned lh[NB];
    for (int i = threadIdx.x; i < NB; i += 256) lh[i] = 0;
    __syncthreads();
    const int e0 = blockIdx.x * RPB;
    #pragma unroll 4
    for (int i = 0; i < RPB / 256; ++i) {
        int dst = ei[N_EDGES + e0 + i * 256 + threadIdx.x];
        atomicAdd(&lh[dst >> 8], 1u);
    }
    __syncthreads();
    for (int i = threadIdx.x; i < NB; i += 256) atomicAdd(&ghist[i], lh[i]);
}

// ---------------- pass 2: exclusive scan -> base, cursor ----------------
__global__ __launch_bounds__(512) void k_scan(const unsigned* __restrict__ ghist,
                                              unsigned* __restrict__ base,
                                              unsigned* __restrict__ cursor) {
    __shared__ unsigned s[512];
    const int t = threadIdx.x;
    unsigned v = (t < NB) ? ghist[t] : 0u;
    s[t] = v; __syncthreads();
    for (int off = 1; off < 512; off <<= 1) {
        unsigned u = (t >= off) ? s[t - off] : 0u;
        __syncthreads();
        s[t] += u;
        __syncthreads();
    }
    if (t < NB) { unsigned ex = s[t] - v; base[t] = ex; cursor[t] = ex; }
    if (t == NB - 1) base[NB] = s[t];   // == N_EDGES
}

// ---------------- pass 3: LDS-staged multisplit partition ----------------
__global__ __launch_bounds__(512) void k_part(const int* __restrict__ ei,
                                              const float* __restrict__ ew,
                                              unsigned* __restrict__ cursor,
                                              uint2* __restrict__ adj) {
    __shared__ uint2    sbuf[RPB];        // 64 KB
    __shared__ unsigned lh[NB], lb[NB + 1], lc[NB], gp[NB];
    __shared__ unsigned sc[512];
    const int t = threadIdx.x;
    for (int i = t; i < NB; i += 512) { lh[i] = 0; lc[i] = 0; }
    __syncthreads();
    const int e0 = blockIdx.x * RPB;
    // histogram this block's 8192 edges
    #pragma unroll 4
    for (int i = 0; i < RPB / 512; ++i) {
        int dst = ei[N_EDGES + e0 + i * 512 + t];
        atomicAdd(&lh[dst >> 8], 1u);
    }
    __syncthreads();
    // local scan
    unsigned v = (t < NB) ? lh[t] : 0u;
    sc[t] = v; __syncthreads();
    for (int off = 1; off < 512; off <<= 1) {
        unsigned u = (t >= off) ? sc[t - off] : 0u;
        __syncthreads();
        sc[t] += u;
        __syncthreads();
    }
    if (t < NB) lb[t] = sc[t] - v;
    if (t == 0) lb[NB] = RPB;
    // allocate global ranges
    if (t < NB) gp[t] = atomicAdd(&cursor[t], lh[t]);
    __syncthreads();
    // scatter into LDS staging (re-read edges)
    #pragma unroll 2
    for (int i = 0; i < RPB / 512; ++i) {
        int e   = e0 + i * 512 + t;
        int src = ei[e];
        int dst = ei[N_EDGES + e];
        float w = ew[e];
        int b = dst >> 8;
        unsigned pos = lb[b] + atomicAdd(&lc[b], 1u);
        sbuf[pos] = make_uint2((unsigned)src | ((unsigned)(dst & 255) << 17),
                               __float_as_uint(w));
    }
    __syncthreads();
    // coalesced copy-out: binary search bucket per slot
    for (int k = t; k < RPB; k += 512) {
        int lo = 0, hi = NB;
        while (hi - lo > 1) {
            int mid = (lo + hi) >> 1;
            if (lb[mid] <= (unsigned)k) lo = mid; else hi = mid;
        }
        adj[gp[lo] + ((unsigned)k - lb[lo])] = sbuf[k];
    }
}

// ---------------- per-bucket degree (no global atomics) ----------------
__global__ __launch_bounds__(256) void k_bdeg(const uint2* __restrict__ adj,
                                              const unsigned* __restrict__ base,
                                              float* __restrict__ deg) {
    __shared__ float sd[BNODES];
    const int t = threadIdx.x, b = blockIdx.x;
    for (int i = t; i < BNODES; i += 256) sd[i] = 0.f;
    __syncthreads();
    const unsigned s0 = base[b], s1 = base[b + 1];
    for (unsigned k = s0 + t; k < s1; k += 256) {
        uint2 e = adj[k];
        atomicAdd(&sd[e.x >> 17], __uint_as_float(e.y));
    }
    __syncthreads();
    for (int i = t; i < BNODES; i += 256) deg[b * BNODES + i] = sd[i];
}

// ---------------- dis = rsqrt(deg + 1) ----------------
__global__ __launch_bounds__(256) void k_dis(const float* __restrict__ deg,
                                             float* __restrict__ dis) {
    int i = blockIdx.x * 256 + threadIdx.x;
    if (i < N_NODES) dis[i] = rsqrtf(deg[i] + 1.0f);
}

// ---------------- h = x @ W1 (fp32 compute, bf16 store) ----------------
__global__ __launch_bounds__(256) void k_h(const float* __restrict__ x,
                                           const float* __restrict__ W1,
                                           unsigned short* __restrict__ hb) {
    __shared__ float w1s[IN_FEAT * HIDDEN];
    __shared__ float xs[64 * IN_FEAT];
    for (int i = threadIdx.x; i < IN_FEAT * HIDDEN; i += 256) w1s[i] = W1[i];
    const int tr = threadIdx.x >> 4;
    const int tc = threadIdx.x & 15;
    for (int t = blockIdx.x; t < N_NODES / 64; t += gridDim.x) {
        const int row0 = t * 64;
        __syncthreads();
        for (int i = threadIdx.x; i < 64 * IN_FEAT; i += 256)
            xs[i] = x[row0 * IN_FEAT + i];
        __syncthreads();
        float acc[4][4] = {};
        for (int k = 0; k < IN_FEAT; ++k) {
            const float4 wv = *(const float4*)&w1s[k * HIDDEN + tc * 4];
            #pragma unroll
            for (int i = 0; i < 4; ++i) {
                const float xv = xs[(tr * 4 + i) * IN_FEAT + k];
                acc[i][0] += xv * wv.x;
                acc[i][1] += xv * wv.y;
                acc[i][2] += xv * wv.z;
                acc[i][3] += xv * wv.w;
            }
        }
        #pragma unroll
        for (int i = 0; i < 4; ++i) {
            ushort4 v;
            v.x = f2bf(acc[i][0]); v.y = f2bf(acc[i][1]);
            v.z = f2bf(acc[i][2]); v.w = f2bf(acc[i][3]);
            *(ushort4*)&hb[(size_t)(row0 + tr * 4 + i) * HIDDEN + tc * 4] = v;
        }
    }
}

// ---------------- W23 = W2 @ W3 ; c0 = b2.W3 + b3 ----------------
__global__ __launch_bounds__(256) void k_w23(const float* __restrict__ W2,
                                             const float* __restrict__ W3,
                                             const float* __restrict__ b2,
                                             const float* __restrict__ b3,
                                             float* __restrict__ W23,
                                             float* __restrict__ c0) {
    const int wid  = blockIdx.x * 4 + (threadIdx.x >> 6);
    const int lane = threadIdx.x & 63;
    if (wid < FDIM) {
        float acc = 0.f;
        #pragma unroll
        for (int c = lane; c < HC2; c += 64) acc += W2[wid * HC2 + c] * W3[c];
        #pragma unroll
        for (int off = 32; off; off >>= 1) acc += __shfl_down(acc, off);
        if (lane == 0) W23[wid] = acc;
    } else if (wid == FDIM) {
        float acc = 0.f;
        #pragma unroll
        for (int c = lane; c < HC2; c += 64) acc += b2[c] * W3[c];
        #pragma unroll
        for (int off = 32; off; off >>= 1) acc += __shfl_down(acc, off);
        if (lane == 0) c0[0] = acc + b3[0];
    }
}

// ---------------- out[g] = c0 ----------------
__global__ __launch_bounds__(256) void k_initout(const float* __restrict__ c0,
                                                 float* __restrict__ out) {
    int g = blockIdx.x * 256 + threadIdx.x;
    if (g < NUM_GRAPHS) out[g] = c0[0];
}

// ---- per-bucket gather + LDS agg + fused epilogue ----
__global__ __launch_bounds__(512) void k_gather(const uint2* __restrict__ adj,
                                                const unsigned* __restrict__ base,
                                                const float* __restrict__ dis,
                                                const unsigned short* __restrict__ hb,
                                                const float* __restrict__ b1,
                                                const float* __restrict__ W23,
                                                float* __restrict__ out) {
    __shared__ float sagg[BNODES * HIDDEN];   // 64 KB
    __shared__ float gacc[4];
    const int t = threadIdx.x, b = blockIdx.x;
    const int wave = t >> 6, lane = t & 63;
    for (int i = t; i < BNODES * HIDDEN; i += 512) sagg[i] = 0.f;
    if (t < 4) gacc[t] = 0.f;
    __syncthreads();
    const unsigned s0 = base[b], s1 = base[b + 1];
    const float b1v = b1[lane];
    for (unsigned c = s0 + wave * 64; c < s1; c += 512) {
        const int rem = (int)(s1 - c);
        uint2 pr = make_uint2(0u, 0u);
        if (lane < rem) pr = adj[c + lane];
        float w_l = (lane < rem) ? __uint_as_float(pr.y) * dis[pr.x & 0x1FFFF] : 0.f;
        int   x_l = (int)pr.x;
        const int lim = rem < 64 ? rem : 64;
        int i = 0;
        for (; i + 4 <= lim; i += 4) {
            int x0 = __shfl(x_l, i),     x1 = __shfl(x_l, i + 1);
            int x2 = __shfl(x_l, i + 2), x3 = __shfl(x_l, i + 3);
            float w0 = __shfl(w_l, i),     w1 = __shfl(w_l, i + 1);
            float w2 = __shfl(w_l, i + 2), w3 = __shfl(w_l, i + 3);
            float h0 = bf2f(hb[(size_t)(x0 & 0x1FFFF) * HIDDEN + lane]);
            float h1 = bf2f(hb[(size_t)(x1 & 0x1FFFF) * HIDDEN + lane]);
            float h2 = bf2f(hb[(size_t)(x2 & 0x1FFFF) * HIDDEN + lane]);
            float h3 = bf2f(hb[(size_t)(x3 & 0x1FFFF) * HIDDEN + lane]);
            atomicAdd(&sagg[(x0 >> 17) * HIDDEN + lane], w0 * h0);
            atomicAdd(&sagg[(x1 >> 17) * HIDDEN + lane], w1 * h1);
            atomicAdd(&sagg[(x2 >> 17) * HIDDEN + lane], w2 * h2);
            atomicAdd(&sagg[(x3 >> 17) * HIDDEN + lane], w3 * h3);
        }
        for (; i < lim; ++i) {
            int   xi = __shfl(x_l, i);
            float wi = __shfl(w_l, i);
            float hv = bf2f(hb[(size_t)(xi & 0x1FFFF) * HIDDEN + lane]);
            atomicAdd(&sagg[(xi >> 17) * HIDDEN + lane], wi * hv);
        }
    }
    __syncthreads();
    // epilogue: 8 waves x 32 nodes
    const int g0 = (b * BNODES) / NPG;
    for (int nl = wave * 32; nl < wave * 32 + 32; ++nl) {
        const int n = b * BNODES + nl;
        const float dn = dis[n];
        const float hv = bf2f(hb[(size_t)n * HIDDEN + lane]);
        float val = sagg[nl * HIDDEN + lane] * dn + hv * dn * dn + b1v;
        val = fmaxf(val, 0.f);
        const int g = n / NPG;
        const int r = n - g * NPG;
        float p = val * W23[r * HIDDEN + lane];
        #pragma unroll
        for (int off = 32; off; off >>= 1) p += __shfl_down(p, off);
        if (lane == 0) atomicAdd(&gacc[g - g0], p);
    }
    __syncthreads();
    const int gmax = (b * BNODES + BNODES - 1) / NPG;
    if (t < 4 && g0 + t <= gmax) atomicAdd(&out[g0 + t], gacc[t]);
}

extern "C" void kernel_launch(void* const* d_in, const int* in_sizes, int n_in,
                              void* d_out, int out_size, void* d_ws, size_t ws_size,
                              hipStream_t stream) {
    const float* x  = (const float*)d_in[0];
    const int*   ei = (const int*)  d_in[1];
    const float* ew = (const float*)d_in[2];
    const float* W1 = (const float*)d_in[4];
    const float* b1 = (const float*)d_in[5];
    const float* W2 = (const float*)d_in[6];
    const float* b2 = (const float*)d_in[7];
    const float* W3 = (const float*)d_in[8];
    const float* b3 = (const float*)d_in[9];
    float* out = (float*)d_out;

    char* ws = (char*)d_ws;
    unsigned short* hb   = (unsigned short*)(ws);              // 15,073,280
    uint2*          adj  = (uint2*)   (ws + 15073280);         // 30,146,560
    float*          deg  = (float*)   (ws + 45219840);         // 471,040
    float*          dis  = (float*)   (ws + 45690880);         // 471,040
    float*          W23  = (float*)   (ws + 46161920);         // 29,440
    unsigned*       ghist= (unsigned*)(ws + 46191360);         // 2,048
    unsigned*       base = (unsigned*)(ws + 46193408);         // 2,048
    unsigned*       cur  = (unsigned*)(ws + 46195456);         // 2,048
    float*          c0   = (float*)   (ws + 46197504);         // 4

    hipMemsetAsync(ghist, 0, NB * sizeof(unsigned), stream);

    k_hist<<<N_EDGES / RPB, 256, 0, stream>>>(ei, ghist);
    k_scan<<<1, 512, 0, stream>>>(ghist, base, cur);
    k_part<<<N_EDGES / RPB, 512, 0, stream>>>(ei, ew, cur, adj);
    k_bdeg<<<NB, 256, 0, stream>>>(adj, base, deg);
    k_dis <<<(N_NODES + 255) / 256, 256, 0, stream>>>(deg, dis);
    k_h   <<<512, 256, 0, stream>>>(x, W1, hb);
    k_w23 <<<(FDIM / 4) + 1, 256, 0, stream>>>(W2, W3, b2, b3, W23, c0);
    k_initout<<<4, 256, 0, stream>>>(c0, out);
    k_gather<<<NB, 512, 0, stream>>>(adj, base, dis, hb, b1, W23, out);
}

// Round 4
// 525.043 us; speedup vs baseline: 3.2648x; 3.2648x over previous
//
#include <hip/hip_runtime.h>

// Problem constants
#define N_NODES    117760
#define N_EDGES    3768320
#define IN_FEAT    115
#define HIDDEN     64
#define NPG        115
#define NUM_GRAPHS 1024
#define HC2        256
#define FDIM       (NPG*HIDDEN)   // 7360
#define NB         460            // buckets (N_NODES / BNODES exactly)
#define BNODES     256            // dst nodes per bucket
#define RPB        8192           // edges per partition block (N_EDGES/RPB = 460)
#define SORT_CHUNK 8192

// adj/adj2 entry: .x = src | (dstlow<<17)  (src < 2^17, dstlow < 256), .y = bits(w)

__device__ __forceinline__ float bf2f(unsigned short u) {
    return __uint_as_float(((unsigned)u) << 16);
}
__device__ __forceinline__ unsigned short f2bf(float f) {
    unsigned x = __float_as_uint(f);
    unsigned r = x + 0x7FFFu + ((x >> 16) & 1u);   // RNE
    return (unsigned short)(r >> 16);
}

// ---------------- pass 1: global bucket histogram ----------------
__global__ __launch_bounds__(256) void k_hist(const int* __restrict__ ei,
                                              unsigned* __restrict__ ghist) {
    __shared__ unsigned lh[NB];
    for (int i = threadIdx.x; i < NB; i += 256) lh[i] = 0;
    __syncthreads();
    const int e0 = blockIdx.x * RPB;
    #pragma unroll 4
    for (int i = 0; i < RPB / 256; ++i) {
        int dst = ei[N_EDGES + e0 + i * 256 + threadIdx.x];
        atomicAdd(&lh[dst >> 8], 1u);
    }
    __syncthreads();
    for (int i = threadIdx.x; i < NB; i += 256) atomicAdd(&ghist[i], lh[i]);
}

// ---------------- pass 2: exclusive scan -> base, cursor ----------------
__global__ __launch_bounds__(512) void k_scan(const unsigned* __restrict__ ghist,
                                              unsigned* __restrict__ base,
                                              unsigned* __restrict__ cursor,
                                              unsigned* __restrict__ base2) {
    __shared__ unsigned s[512];
    const int t = threadIdx.x;
    unsigned v = (t < NB) ? ghist[t] : 0u;
    s[t] = v; __syncthreads();
    for (int off = 1; off < 512; off <<= 1) {
        unsigned u = (t >= off) ? s[t - off] : 0u;
        __syncthreads();
        s[t] += u;
        __syncthreads();
    }
    if (t < NB) { unsigned ex = s[t] - v; base[t] = ex; cursor[t] = ex; }
    if (t == NB - 1) base[NB] = s[t];
    if (t == 0) base2[N_NODES] = N_EDGES;
}

// ---------------- pass 3: LDS-staged multisplit partition (by bucket) ----
__global__ __launch_bounds__(512) void k_part(const int* __restrict__ ei,
                                              const float* __restrict__ ew,
                                              unsigned* __restrict__ cursor,
                                              uint2* __restrict__ adj) {
    __shared__ uint2    sbuf[RPB];        // 64 KB
    __shared__ unsigned lh[NB], lb[NB + 1], lc[NB], gp[NB];
    __shared__ unsigned sc[512];
    const int t = threadIdx.x;
    for (int i = t; i < NB; i += 512) { lh[i] = 0; lc[i] = 0; }
    __syncthreads();
    const int e0 = blockIdx.x * RPB;
    #pragma unroll 4
    for (int i = 0; i < RPB / 512; ++i) {
        int dst = ei[N_EDGES + e0 + i * 512 + t];
        atomicAdd(&lh[dst >> 8], 1u);
    }
    __syncthreads();
    unsigned v = (t < NB) ? lh[t] : 0u;
    sc[t] = v; __syncthreads();
    for (int off = 1; off < 512; off <<= 1) {
        unsigned u = (t >= off) ? sc[t - off] : 0u;
        __syncthreads();
        sc[t] += u;
        __syncthreads();
    }
    if (t < NB) lb[t] = sc[t] - v;
    if (t == 0) lb[NB] = RPB;
    if (t < NB) gp[t] = atomicAdd(&cursor[t], lh[t]);
    __syncthreads();
    #pragma unroll 2
    for (int i = 0; i < RPB / 512; ++i) {
        int e   = e0 + i * 512 + t;
        int src = ei[e];
        int dst = ei[N_EDGES + e];
        float w = ew[e];
        int b = dst >> 8;
        unsigned pos = lb[b] + atomicAdd(&lc[b], 1u);
        sbuf[pos] = make_uint2((unsigned)src | ((unsigned)(dst & 255) << 17),
                               __float_as_uint(w));
    }
    __syncthreads();
    for (int k = t; k < RPB; k += 512) {
        int lo = 0, hi = NB;
        while (hi - lo > 1) {
            int mid = (lo + hi) >> 1;
            if (lb[mid] <= (unsigned)k) lo = mid; else hi = mid;
        }
        adj[gp[lo] + ((unsigned)k - lb[lo])] = sbuf[k];
    }
}

// ---- pass 4: per-bucket sort by dst node -> adj2 + per-node CSR + dis ----
__global__ __launch_bounds__(512) void k_sort2(const uint2* __restrict__ adj,
                                               const unsigned* __restrict__ base,
                                               uint2* __restrict__ adj2,
                                               unsigned* __restrict__ base2,
                                               float* __restrict__ dis) {
    __shared__ uint2    sbuf[SORT_CHUNK];   // 64 KB
    __shared__ unsigned lh[256], lb[257], ch[256], cb[257], lcc[256], gp2[256];
    __shared__ float    sdeg[256];
    __shared__ unsigned sc[512];
    const int t = threadIdx.x, b = blockIdx.x;
    const unsigned s0 = base[b], s1 = base[b + 1];
    if (t < 256) { lh[t] = 0; sdeg[t] = 0.f; }
    __syncthreads();
    // full-bucket hist + weighted degree
    for (unsigned k = s0 + t; k < s1; k += 512) {
        uint2 e = adj[k];
        unsigned dl = e.x >> 17;
        atomicAdd(&lh[dl], 1u);
        atomicAdd(&sdeg[dl], __uint_as_float(e.y));
    }
    __syncthreads();
    // exclusive scan lh -> lb
    unsigned v = (t < 256) ? lh[t] : 0u;
    sc[t] = v; __syncthreads();
    for (int off = 1; off < 256; off <<= 1) {
        unsigned u = (t >= off && t < 256) ? sc[t - off] : 0u;
        __syncthreads();
        if (t < 256) sc[t] += u;
        __syncthreads();
    }
    if (t < 256) {
        lb[t]  = sc[t] - v;
        gp2[t] = s0 + sc[t] - v;
        base2[b * 256 + t] = s0 + sc[t] - v;
        dis[b * 256 + t]   = rsqrtf(sdeg[t] + 1.0f);
    }
    if (t == 255) lb[256] = sc[255];
    __syncthreads();

    if (s1 - s0 <= (unsigned)SORT_CHUNK) {
        // fast path: single chunk, copy-out is linear
        if (t < 256) lcc[t] = 0;
        __syncthreads();
        for (unsigned k = s0 + t; k < s1; k += 512) {
            uint2 e = adj[k];
            unsigned dl = e.x >> 17;
            sbuf[lb[dl] + atomicAdd(&lcc[dl], 1u)] = e;
        }
        __syncthreads();
        const int csz = (int)(s1 - s0);
        for (int k = t; k < csz; k += 512) adj2[s0 + k] = sbuf[k];
    } else {
        // general chunked path (statistically near-never, correctness-safe)
        for (unsigned cst = s0; cst < s1; cst += SORT_CHUNK) {
            const unsigned cend = (cst + SORT_CHUNK < s1) ? cst + SORT_CHUNK : s1;
            const int csz = (int)(cend - cst);
            if (t < 256) { ch[t] = 0; lcc[t] = 0; }
            __syncthreads();
            for (unsigned k = cst + t; k < cend; k += 512)
                atomicAdd(&ch[adj[k].x >> 17], 1u);
            __syncthreads();
            unsigned v2 = (t < 256) ? ch[t] : 0u;
            sc[t] = v2; __syncthreads();
            for (int off = 1; off < 256; off <<= 1) {
                unsigned u = (t >= off && t < 256) ? sc[t - off] : 0u;
                __syncthreads();
                if (t < 256) sc[t] += u;
                __syncthreads();
            }
            if (t < 256) cb[t] = sc[t] - v2;
            if (t == 255) cb[256] = sc[255];
            __syncthreads();
            for (unsigned k = cst + t; k < cend; k += 512) {
                uint2 e = adj[k];
                unsigned dl = e.x >> 17;
                sbuf[cb[dl] + atomicAdd(&lcc[dl], 1u)] = e;
            }
            __syncthreads();
            for (int k = t; k < csz; k += 512) {
                int lo = 0, hi = 256;
                while (hi - lo > 1) {
                    int mid = (lo + hi) >> 1;
                    if (cb[mid] <= (unsigned)k) lo = mid; else hi = mid;
                }
                adj2[gp2[lo] + ((unsigned)k - cb[lo])] = sbuf[k];
            }
            __syncthreads();
            if (t < 256) gp2[t] += ch[t];
            __syncthreads();
        }
    }
}

// ---- pass 5: fold w *= dis[src] into edge records ----
__global__ __launch_bounds__(256) void k_fold(uint2* __restrict__ adj2,
                                              const float* __restrict__ dis) {
    int k = blockIdx.x * 256 + threadIdx.x;
    uint2 e = adj2[k];
    adj2[k].y = __float_as_uint(__uint_as_float(e.y) * dis[e.x & 0x1FFFF]);
}

// ---------------- h = x @ W1 (fp32 compute, bf16 store) ----------------
__global__ __launch_bounds__(256) void k_h(const float* __restrict__ x,
                                           const float* __restrict__ W1,
                                           unsigned short* __restrict__ hb) {
    __shared__ float w1s[IN_FEAT * HIDDEN];
    __shared__ float xs[64 * IN_FEAT];
    for (int i = threadIdx.x; i < IN_FEAT * HIDDEN; i += 256) w1s[i] = W1[i];
    const int tr = threadIdx.x >> 4;
    const int tc = threadIdx.x & 15;
    for (int t = blockIdx.x; t < N_NODES / 64; t += gridDim.x) {
        const int row0 = t * 64;
        __syncthreads();
        for (int i = threadIdx.x; i < 64 * IN_FEAT; i += 256)
            xs[i] = x[row0 * IN_FEAT + i];
        __syncthreads();
        float acc[4][4] = {};
        for (int k = 0; k < IN_FEAT; ++k) {
            const float4 wv = *(const float4*)&w1s[k * HIDDEN + tc * 4];
            #pragma unroll
            for (int i = 0; i < 4; ++i) {
                const float xv = xs[(tr * 4 + i) * IN_FEAT + k];
                acc[i][0] += xv * wv.x;
                acc[i][1] += xv * wv.y;
                acc[i][2] += xv * wv.z;
                acc[i][3] += xv * wv.w;
            }
        }
        #pragma unroll
        for (int i = 0; i < 4; ++i) {
            ushort4 v;
            v.x = f2bf(acc[i][0]); v.y = f2bf(acc[i][1]);
            v.z = f2bf(acc[i][2]); v.w = f2bf(acc[i][3]);
            *(ushort4*)&hb[(size_t)(row0 + tr * 4 + i) * HIDDEN + tc * 4] = v;
        }
    }
}

// ---------------- W23 = W2 @ W3 ; c0 = b2.W3 + b3 ----------------
__global__ __launch_bounds__(256) void k_w23(const float* __restrict__ W2,
                                             const float* __restrict__ W3,
                                             const float* __restrict__ b2,
                                             const float* __restrict__ b3,
                                             float* __restrict__ W23,
                                             float* __restrict__ c0) {
    const int wid  = blockIdx.x * 4 + (threadIdx.x >> 6);
    const int lane = threadIdx.x & 63;
    if (wid < FDIM) {
        float acc = 0.f;
        #pragma unroll
        for (int c = lane; c < HC2; c += 64) acc += W2[wid * HC2 + c] * W3[c];
        #pragma unroll
        for (int off = 32; off; off >>= 1) acc += __shfl_down(acc, off);
        if (lane == 0) W23[wid] = acc;
    } else if (wid == FDIM) {
        float acc = 0.f;
        #pragma unroll
        for (int c = lane; c < HC2; c += 64) acc += b2[c] * W3[c];
        #pragma unroll
        for (int off = 32; off; off >>= 1) acc += __shfl_down(acc, off);
        if (lane == 0) c0[0] = acc + b3[0];
    }
}

// ---------------- out[g] = c0 ----------------
__global__ __launch_bounds__(256) void k_initout(const float* __restrict__ c0,
                                                 float* __restrict__ out) {
    int g = blockIdx.x * 256 + threadIdx.x;
    if (g < NUM_GRAPHS) out[g] = c0[0];
}

// ---- pass 6: gather (wave per node, registers only) + fused epilogue ----
__global__ __launch_bounds__(256) void k_gather(const uint2* __restrict__ adj2,
                                                const unsigned* __restrict__ base2,
                                                const float* __restrict__ dis,
                                                const unsigned short* __restrict__ hb,
                                                const float* __restrict__ b1,
                                                const float* __restrict__ W23,
                                                float* __restrict__ out) {
    const int wave = threadIdx.x >> 6, lane = threadIdx.x & 63;
    const int n = blockIdx.x * 4 + wave;
    const unsigned s0 = __builtin_amdgcn_readfirstlane(base2[n]);
    const unsigned s1 = __builtin_amdgcn_readfirstlane(base2[n + 1]);
    const float dn = dis[n];
    float acc = 0.f;
    unsigned c = s0;
    for (; c + 8 <= s1; c += 8) {
        uint2 e0 = adj2[c + 0], e1 = adj2[c + 1], e2 = adj2[c + 2], e3 = adj2[c + 3];
        uint2 e4 = adj2[c + 4], e5 = adj2[c + 5], e6 = adj2[c + 6], e7 = adj2[c + 7];
        float h0 = bf2f(hb[(size_t)(e0.x & 0x1FFFF) * HIDDEN + lane]);
        float h1 = bf2f(hb[(size_t)(e1.x & 0x1FFFF) * HIDDEN + lane]);
        float h2 = bf2f(hb[(size_t)(e2.x & 0x1FFFF) * HIDDEN + lane]);
        float h3 = bf2f(hb[(size_t)(e3.x & 0x1FFFF) * HIDDEN + lane]);
        float h4 = bf2f(hb[(size_t)(e4.x & 0x1FFFF) * HIDDEN + lane]);
        float h5 = bf2f(hb[(size_t)(e5.x & 0x1FFFF) * HIDDEN + lane]);
        float h6 = bf2f(hb[(size_t)(e6.x & 0x1FFFF) * HIDDEN + lane]);
        float h7 = bf2f(hb[(size_t)(e7.x & 0x1FFFF) * HIDDEN + lane]);
        acc += __uint_as_float(e0.y) * h0; acc += __uint_as_float(e1.y) * h1;
        acc += __uint_as_float(e2.y) * h2; acc += __uint_as_float(e3.y) * h3;
        acc += __uint_as_float(e4.y) * h4; acc += __uint_as_float(e5.y) * h5;
        acc += __uint_as_float(e6.y) * h6; acc += __uint_as_float(e7.y) * h7;
    }
    for (; c < s1; ++c) {
        uint2 e = adj2[c];
        acc += __uint_as_float(e.y) * bf2f(hb[(size_t)(e.x & 0x1FFFF) * HIDDEN + lane]);
    }
    const float hn = bf2f(hb[(size_t)n * HIDDEN + lane]);
    float val = fmaxf(acc * dn + hn * dn * dn + b1[lane], 0.f);
    const int g = n / NPG;
    const int r = n - g * NPG;
    float p = val * W23[r * HIDDEN + lane];
    #pragma unroll
    for (int off = 32; off; off >>= 1) p += __shfl_down(p, off);
    if (lane == 0) atomicAdd(&out[g], p);
}

extern "C" void kernel_launch(void* const* d_in, const int* in_sizes, int n_in,
                              void* d_out, int out_size, void* d_ws, size_t ws_size,
                              hipStream_t stream) {
    const float* x  = (const float*)d_in[0];
    const int*   ei = (const int*)  d_in[1];
    const float* ew = (const float*)d_in[2];
    const float* W1 = (const float*)d_in[4];
    const float* b1 = (const float*)d_in[5];
    const float* W2 = (const float*)d_in[6];
    const float* b2 = (const float*)d_in[7];
    const float* W3 = (const float*)d_in[8];
    const float* b3 = (const float*)d_in[9];
    float* out = (float*)d_out;

    char* ws = (char*)d_ws;
    unsigned short* hb   = (unsigned short*)(ws);              // 15,073,280
    uint2*          adj  = (uint2*)   (ws + 15073280);         // 30,146,560
    uint2*          adj2 = (uint2*)   (ws + 45219840);         // 30,146,560
    float*          dis  = (float*)   (ws + 75366400);         // 471,040
    unsigned*       base2= (unsigned*)(ws + 75837440);         // 471,048
    unsigned*       ghist= (unsigned*)(ws + 76308488);         // 1,848
    unsigned*       base = (unsigned*)(ws + 76310336);         // 1,848
    unsigned*       cur  = (unsigned*)(ws + 76312184);         // 1,848
    float*          W23  = (float*)   (ws + 76314032);         // 29,440
    float*          c0   = (float*)   (ws + 76343472);         // 4

    hipMemsetAsync(ghist, 0, NB * sizeof(unsigned), stream);

    k_hist <<<NB, 256, 0, stream>>>(ei, ghist);
    k_scan <<<1, 512, 0, stream>>>(ghist, base, cur, base2);
    k_part <<<NB, 512, 0, stream>>>(ei, ew, cur, adj);
    k_sort2<<<NB, 512, 0, stream>>>(adj, base, adj2, base2, dis);
    k_fold <<<N_EDGES / 256, 256, 0, stream>>>(adj2, dis);
    k_h    <<<512, 256, 0, stream>>>(x, W1, hb);
    k_w23  <<<(FDIM / 4) + 1, 256, 0, stream>>>(W2, W3, b2, b3, W23, c0);
    k_initout<<<4, 256, 0, stream>>>(c0, out);
    k_gather<<<N_NODES / 4, 256, 0, stream>>>(adj2, base2, dis, hb, b1, W23, out);
}

// Round 5
// 435.202 us; speedup vs baseline: 3.9388x; 1.2064x over previous
//
#include <hip/hip_runtime.h>

// Problem constants
#define N_NODES    117760
#define N_EDGES    3768320
#define IN_FEAT    115
#define HIDDEN     64
#define NPG        115
#define NUM_GRAPHS 1024
#define HC2        256
#define FDIM       (NPG*HIDDEN)   // 7360
#define NB         460            // buckets (N_NODES / BNODES exactly)
#define BNODES     256            // dst nodes per bucket
#define RPB        8192           // edges per partition block (N_EDGES/RPB = 460)
#define SORT_CAP   8704           // per-bucket LDS capacity (mean 8192, sd ~90)

// adj/adj2 entry: .x = src | (dstlow<<17)  (src < 2^17, dstlow < 256), .y = bits(w)

__device__ __forceinline__ float bf2f(unsigned short u) {
    return __uint_as_float(((unsigned)u) << 16);
}
__device__ __forceinline__ unsigned short f2bf(float f) {
    unsigned x = __float_as_uint(f);
    unsigned r = x + 0x7FFFu + ((x >> 16) & 1u);   // RNE
    return (unsigned short)(r >> 16);
}

// ---------------- pass 1: global bucket histogram ----------------
__global__ __launch_bounds__(256) void k_hist(const int* __restrict__ ei,
                                              unsigned* __restrict__ ghist) {
    __shared__ unsigned lh[NB];
    for (int i = threadIdx.x; i < NB; i += 256) lh[i] = 0;
    __syncthreads();
    const int e0 = blockIdx.x * RPB;
    #pragma unroll 4
    for (int i = 0; i < RPB / 256; ++i) {
        int dst = ei[N_EDGES + e0 + i * 256 + threadIdx.x];
        atomicAdd(&lh[dst >> 8], 1u);
    }
    __syncthreads();
    for (int i = threadIdx.x; i < NB; i += 256) atomicAdd(&ghist[i], lh[i]);
}

// ---------------- pass 2: exclusive scan -> base, cursor ----------------
__global__ __launch_bounds__(512) void k_scan(const unsigned* __restrict__ ghist,
                                              unsigned* __restrict__ base,
                                              unsigned* __restrict__ cursor,
                                              unsigned* __restrict__ base2) {
    __shared__ unsigned s[512];
    const int t = threadIdx.x;
    unsigned v = (t < NB) ? ghist[t] : 0u;
    s[t] = v; __syncthreads();
    for (int off = 1; off < 512; off <<= 1) {
        unsigned u = (t >= off) ? s[t - off] : 0u;
        __syncthreads();
        s[t] += u;
        __syncthreads();
    }
    if (t < NB) { unsigned ex = s[t] - v; base[t] = ex; cursor[t] = ex; }
    if (t == NB - 1) base[NB] = s[t];
    if (t == 0) base2[N_NODES] = N_EDGES;
}

// ---------------- pass 3: LDS-staged multisplit partition (by bucket) ----
// sc[512] doubles as hist + scan buffer; sbkt tags each staged slot with
// bucket low-8 (disambiguated via lb monotonicity) -> no binary search.
__global__ __launch_bounds__(512) void k_part(const int* __restrict__ ei,
                                              const float* __restrict__ ew,
                                              unsigned* __restrict__ cursor,
                                              uint2* __restrict__ adj) {
    __shared__ uint2         sbuf[RPB];        // 64 KB
    __shared__ unsigned char sbkt[RPB];        // 8 KB
    __shared__ unsigned      lb[NB + 1], lc[NB], gp[NB];
    __shared__ unsigned      sc[512];
    const int t = threadIdx.x;
    sc[t] = 0;
    for (int i = t; i < NB; i += 512) lc[i] = 0;
    __syncthreads();
    const int e0 = blockIdx.x * RPB;
    #pragma unroll 4
    for (int i = 0; i < RPB / 512; ++i) {
        int dst = ei[N_EDGES + e0 + i * 512 + t];
        atomicAdd(&sc[dst >> 8], 1u);
    }
    __syncthreads();
    const unsigned v = sc[t];          // own bucket count (t<NB), else 0
    __syncthreads();
    for (int off = 1; off < 512; off <<= 1) {
        unsigned u = (t >= off) ? sc[t - off] : 0u;
        __syncthreads();
        sc[t] += u;
        __syncthreads();
    }
    if (t < NB) lb[t] = sc[t] - v;
    if (t == NB - 1) lb[NB] = sc[t];
    if (t < NB) gp[t] = atomicAdd(&cursor[t], v);
    __syncthreads();
    #pragma unroll 2
    for (int i = 0; i < RPB / 512; ++i) {
        int e   = e0 + i * 512 + t;
        int src = ei[e];
        int dst = ei[N_EDGES + e];
        float w = ew[e];
        int b = dst >> 8;
        unsigned pos = lb[b] + atomicAdd(&lc[b], 1u);
        sbuf[pos] = make_uint2((unsigned)src | ((unsigned)(dst & 255) << 17),
                               __float_as_uint(w));
        sbkt[pos] = (unsigned char)b;
    }
    __syncthreads();
    for (int k = t; k < RPB; k += 512) {
        int b = (int)sbkt[k];
        if ((unsigned)k >= lb[b + 1]) b += 256;   // low-8 disambiguation
        adj[gp[b] + ((unsigned)k - lb[b])] = sbuf[k];
    }
}

// ---- pass 4: per-bucket sort by dst node -> adj2 + per-node CSR + dis ----
__global__ __launch_bounds__(512) void k_sort2(const uint2* __restrict__ adj,
                                               const unsigned* __restrict__ base,
                                               uint2* __restrict__ adj2,
                                               unsigned* __restrict__ base2,
                                               float* __restrict__ dis) {
    __shared__ uint2    sbuf[SORT_CAP];   // 68 KB
    __shared__ unsigned lh[256], lb[257], ch[256], cb[257], lcc[256], gp2[256];
    __shared__ float    sdeg[256];
    __shared__ unsigned sc[512];
    const int t = threadIdx.x, b = blockIdx.x;
    const unsigned s0 = base[b], s1 = base[b + 1];
    if (t < 256) { lh[t] = 0; sdeg[t] = 0.f; }
    __syncthreads();
    // full-bucket hist + weighted degree
    for (unsigned k = s0 + t; k < s1; k += 512) {
        uint2 e = adj[k];
        unsigned dl = e.x >> 17;
        atomicAdd(&lh[dl], 1u);
        atomicAdd(&sdeg[dl], __uint_as_float(e.y));
    }
    __syncthreads();
    // exclusive scan lh -> lb
    unsigned v = (t < 256) ? lh[t] : 0u;
    sc[t] = v; __syncthreads();
    for (int off = 1; off < 256; off <<= 1) {
        unsigned u = (t >= off && t < 256) ? sc[t - off] : 0u;
        __syncthreads();
        if (t < 256) sc[t] += u;
        __syncthreads();
    }
    if (t < 256) {
        lb[t]  = sc[t] - v;
        gp2[t] = s0 + sc[t] - v;
        base2[b * 256 + t] = s0 + sc[t] - v;
        dis[b * 256 + t]   = rsqrtf(sdeg[t] + 1.0f);
    }
    if (t == 255) lb[256] = sc[255];
    __syncthreads();

    if (s1 - s0 <= (unsigned)SORT_CAP) {
        // fast path: whole bucket staged, copy-out is linear
        if (t < 256) lcc[t] = 0;
        __syncthreads();
        for (unsigned k = s0 + t; k < s1; k += 512) {
            uint2 e = adj[k];
            unsigned dl = e.x >> 17;
            sbuf[lb[dl] + atomicAdd(&lcc[dl], 1u)] = e;
        }
        __syncthreads();
        const int csz = (int)(s1 - s0);
        for (int k = t; k < csz; k += 512) adj2[s0 + k] = sbuf[k];
    } else {
        // general chunked path (statistically near-never, correctness-safe)
        for (unsigned cst = s0; cst < s1; cst += SORT_CAP) {
            const unsigned cend = (cst + SORT_CAP < s1) ? cst + SORT_CAP : s1;
            const int csz = (int)(cend - cst);
            if (t < 256) { ch[t] = 0; lcc[t] = 0; }
            __syncthreads();
            for (unsigned k = cst + t; k < cend; k += 512)
                atomicAdd(&ch[adj[k].x >> 17], 1u);
            __syncthreads();
            unsigned v2 = (t < 256) ? ch[t] : 0u;
            sc[t] = v2; __syncthreads();
            for (int off = 1; off < 256; off <<= 1) {
                unsigned u = (t >= off && t < 256) ? sc[t - off] : 0u;
                __syncthreads();
                if (t < 256) sc[t] += u;
                __syncthreads();
            }
            if (t < 256) cb[t] = sc[t] - v2;
            if (t == 255) cb[256] = sc[255];
            __syncthreads();
            for (unsigned k = cst + t; k < cend; k += 512) {
                uint2 e = adj[k];
                unsigned dl = e.x >> 17;
                sbuf[cb[dl] + atomicAdd(&lcc[dl], 1u)] = e;
            }
            __syncthreads();
            for (int k = t; k < csz; k += 512) {
                int lo = 0, hi = 256;
                while (hi - lo > 1) {
                    int mid = (lo + hi) >> 1;
                    if (cb[mid] <= (unsigned)k) lo = mid; else hi = mid;
                }
                adj2[gp2[lo] + ((unsigned)k - cb[lo])] = sbuf[k];
            }
            __syncthreads();
            if (t < 256) gp2[t] += ch[t];
            __syncthreads();
        }
    }
}

// ------- h2 = (x @ W1) * dis[row]  (fp32 compute, bf16 store) -------
__global__ __launch_bounds__(256) void k_h(const float* __restrict__ x,
                                           const float* __restrict__ W1,
                                           const float* __restrict__ dis,
                                           unsigned short* __restrict__ hb2) {
    __shared__ float w1s[IN_FEAT * HIDDEN];
    __shared__ float xs[64 * IN_FEAT];
    for (int i = threadIdx.x; i < IN_FEAT * HIDDEN; i += 256) w1s[i] = W1[i];
    const int tr = threadIdx.x >> 4;
    const int tc = threadIdx.x & 15;
    for (int t = blockIdx.x; t < N_NODES / 64; t += gridDim.x) {
        const int row0 = t * 64;
        __syncthreads();
        for (int i = threadIdx.x; i < 64 * IN_FEAT; i += 256)
            xs[i] = x[row0 * IN_FEAT + i];
        __syncthreads();
        float acc[4][4] = {};
        for (int k = 0; k < IN_FEAT; ++k) {
            const float4 wv = *(const float4*)&w1s[k * HIDDEN + tc * 4];
            #pragma unroll
            for (int i = 0; i < 4; ++i) {
                const float xv = xs[(tr * 4 + i) * IN_FEAT + k];
                acc[i][0] += xv * wv.x;
                acc[i][1] += xv * wv.y;
                acc[i][2] += xv * wv.z;
                acc[i][3] += xv * wv.w;
            }
        }
        #pragma unroll
        for (int i = 0; i < 4; ++i) {
            const int row = row0 + tr * 4 + i;
            const float dn = dis[row];
            ushort4 v;
            v.x = f2bf(acc[i][0] * dn); v.y = f2bf(acc[i][1] * dn);
            v.z = f2bf(acc[i][2] * dn); v.w = f2bf(acc[i][3] * dn);
            *(ushort4*)&hb2[(size_t)row * HIDDEN + tc * 4] = v;
        }
    }
}

// ---------------- W23 = W2 @ W3 ; c0 = b2.W3 + b3 ----------------
__global__ __launch_bounds__(256) void k_w23(const float* __restrict__ W2,
                                             const float* __restrict__ W3,
                                             const float* __restrict__ b2,
                                             const float* __restrict__ b3,
                                             float* __restrict__ W23,
                                             float* __restrict__ c0) {
    const int wid  = blockIdx.x * 4 + (threadIdx.x >> 6);
    const int lane = threadIdx.x & 63;
    if (wid < FDIM) {
        float acc = 0.f;
        #pragma unroll
        for (int c = lane; c < HC2; c += 64) acc += W2[wid * HC2 + c] * W3[c];
        #pragma unroll
        for (int off = 32; off; off >>= 1) acc += __shfl_down(acc, off);
        if (lane == 0) W23[wid] = acc;
    } else if (wid == FDIM) {
        float acc = 0.f;
        #pragma unroll
        for (int c = lane; c < HC2; c += 64) acc += b2[c] * W3[c];
        #pragma unroll
        for (int off = 32; off; off >>= 1) acc += __shfl_down(acc, off);
        if (lane == 0) c0[0] = acc + b3[0];
    }
}

// ---------------- out[g] = c0 ----------------
__global__ __launch_bounds__(256) void k_initout(const float* __restrict__ c0,
                                                 float* __restrict__ out) {
    int g = blockIdx.x * 256 + threadIdx.x;
    if (g < NUM_GRAPHS) out[g] = c0[0];
}

// 8-edge gather step: 8B records are wave-uniform (SGPR) loads, gathers 128B rows
__device__ __forceinline__ float gath8(const uint2* __restrict__ adj2, unsigned c,
                                       const unsigned short* __restrict__ hb2, int lane) {
    uint2 e0 = adj2[c + 0], e1 = adj2[c + 1], e2 = adj2[c + 2], e3 = adj2[c + 3];
    uint2 e4 = adj2[c + 4], e5 = adj2[c + 5], e6 = adj2[c + 6], e7 = adj2[c + 7];
    float h0 = bf2f(hb2[(size_t)(e0.x & 0x1FFFF) * HIDDEN + lane]);
    float h1 = bf2f(hb2[(size_t)(e1.x & 0x1FFFF) * HIDDEN + lane]);
    float h2 = bf2f(hb2[(size_t)(e2.x & 0x1FFFF) * HIDDEN + lane]);
    float h3 = bf2f(hb2[(size_t)(e3.x & 0x1FFFF) * HIDDEN + lane]);
    float h4 = bf2f(hb2[(size_t)(e4.x & 0x1FFFF) * HIDDEN + lane]);
    float h5 = bf2f(hb2[(size_t)(e5.x & 0x1FFFF) * HIDDEN + lane]);
    float h6 = bf2f(hb2[(size_t)(e6.x & 0x1FFFF) * HIDDEN + lane]);
    float h7 = bf2f(hb2[(size_t)(e7.x & 0x1FFFF) * HIDDEN + lane]);
    float s = 0.f;
    s += __uint_as_float(e0.y) * h0; s += __uint_as_float(e1.y) * h1;
    s += __uint_as_float(e2.y) * h2; s += __uint_as_float(e3.y) * h3;
    s += __uint_as_float(e4.y) * h4; s += __uint_as_float(e5.y) * h5;
    s += __uint_as_float(e6.y) * h6; s += __uint_as_float(e7.y) * h7;
    return s;
}

// ---- pass 5: gather, 2 nodes per wave (interleaved for MLP) + epilogue ----
__global__ __launch_bounds__(256) void k_gather(const uint2* __restrict__ adj2,
                                                const unsigned* __restrict__ base2,
                                                const float* __restrict__ dis,
                                                const unsigned short* __restrict__ hb2,
                                                const float* __restrict__ b1,
                                                const float* __restrict__ W23,
                                                float* __restrict__ out) {
    const int wave = threadIdx.x >> 6, lane = threadIdx.x & 63;
    const int n0 = blockIdx.x * 8 + wave * 2;        // grid = N_NODES/8
    const unsigned sa0 = __builtin_amdgcn_readfirstlane(base2[n0]);
    const unsigned sa1 = __builtin_amdgcn_readfirstlane(base2[n0 + 1]);
    const unsigned sb1 = __builtin_amdgcn_readfirstlane(base2[n0 + 2]);
    float acc0 = 0.f, acc1 = 0.f;
    unsigned ca = sa0, cb = sa1;
    while (ca + 8 <= sa1 && cb + 8 <= sb1) {         // 16 gathers in flight
        acc0 += gath8(adj2, ca, hb2, lane);
        acc1 += gath8(adj2, cb, hb2, lane);
        ca += 8; cb += 8;
    }
    for (; ca + 8 <= sa1; ca += 8) acc0 += gath8(adj2, ca, hb2, lane);
    for (; cb + 8 <= sb1; cb += 8) acc1 += gath8(adj2, cb, hb2, lane);
    for (; ca < sa1; ++ca) {
        uint2 e = adj2[ca];
        acc0 += __uint_as_float(e.y) * bf2f(hb2[(size_t)(e.x & 0x1FFFF) * HIDDEN + lane]);
    }
    for (; cb < sb1; ++cb) {
        uint2 e = adj2[cb];
        acc1 += __uint_as_float(e.y) * bf2f(hb2[(size_t)(e.x & 0x1FFFF) * HIDDEN + lane]);
    }
    // epilogue for both nodes: val = (acc + hb2[n])*dis[n] + b1 ; relu ; dot W23
    const float dn0 = dis[n0], dn1 = dis[n0 + 1];
    const float s20 = bf2f(hb2[(size_t)n0 * HIDDEN + lane]);
    const float s21 = bf2f(hb2[(size_t)(n0 + 1) * HIDDEN + lane]);
    const float b1v = b1[lane];
    float v0 = fmaxf((acc0 + s20) * dn0 + b1v, 0.f);
    float v1 = fmaxf((acc1 + s21) * dn1 + b1v, 0.f);
    const int g0 = n0 / NPG,       r0 = n0 - g0 * NPG;
    const int g1 = (n0 + 1) / NPG, r1 = (n0 + 1) - g1 * NPG;
    float p0 = v0 * W23[r0 * HIDDEN + lane];
    float p1 = v1 * W23[r1 * HIDDEN + lane];
    #pragma unroll
    for (int off = 32; off; off >>= 1) {
        p0 += __shfl_down(p0, off);
        p1 += __shfl_down(p1, off);
    }
    if (lane == 0) {
        atomicAdd(&out[g0], p0);
        atomicAdd(&out[g1], p1);
    }
}

extern "C" void kernel_launch(void* const* d_in, const int* in_sizes, int n_in,
                              void* d_out, int out_size, void* d_ws, size_t ws_size,
                              hipStream_t stream) {
    const float* x  = (const float*)d_in[0];
    const int*   ei = (const int*)  d_in[1];
    const float* ew = (const float*)d_in[2];
    const float* W1 = (const float*)d_in[4];
    const float* b1 = (const float*)d_in[5];
    const float* W2 = (const float*)d_in[6];
    const float* b2 = (const float*)d_in[7];
    const float* W3 = (const float*)d_in[8];
    const float* b3 = (const float*)d_in[9];
    float* out = (float*)d_out;

    char* ws = (char*)d_ws;
    unsigned short* hb2  = (unsigned short*)(ws);              // 15,073,280
    uint2*          adj  = (uint2*)   (ws + 15073280);         // 30,146,560
    uint2*          adj2 = (uint2*)   (ws + 45219840);         // 30,146,560
    float*          dis  = (float*)   (ws + 75366400);         // 471,040
    unsigned*       base2= (unsigned*)(ws + 75837440);         // 471,044
    unsigned*       ghist= (unsigned*)(ws + 76308488);         // 1,840
    unsigned*       base = (unsigned*)(ws + 76310328);         // 1,844
    unsigned*       cur  = (unsigned*)(ws + 76312172);         // 1,840
    float*          W23  = (float*)   (ws + 76314016);         // 29,440
    float*          c0   = (float*)   (ws + 76343456);         // 4

    hipMemsetAsync(ghist, 0, NB * sizeof(unsigned), stream);

    k_hist <<<NB, 256, 0, stream>>>(ei, ghist);
    k_scan <<<1, 512, 0, stream>>>(ghist, base, cur, base2);
    k_part <<<NB, 512, 0, stream>>>(ei, ew, cur, adj);
    k_sort2<<<NB, 512, 0, stream>>>(adj, base, adj2, base2, dis);
    k_h    <<<512, 256, 0, stream>>>(x, W1, dis, hb2);
    k_w23  <<<(FDIM / 4) + 1, 256, 0, stream>>>(W2, W3, b2, b3, W23, c0);
    k_initout<<<4, 256, 0, stream>>>(c0, out);
    k_gather<<<N_NODES / 8, 256, 0, stream>>>(adj2, base2, dis, hb2, b1, W23, out);
}